// Round 6
// baseline (241.598 us; speedup 1.0000x reference)
//
#include <hip/hip_runtime.h>

#define NS 256
#define NW 128
#define NH 768
#define NL 384          // TOPK*W keys
#define WH (NW*NH)      // 98304
#define OUTROWS 127

typedef __attribute__((ext_vector_type(8))) short short8;
typedef __attribute__((ext_vector_type(8))) unsigned short ushort8;
typedef __attribute__((ext_vector_type(8))) __bf16 bf16x8;
typedef __attribute__((ext_vector_type(4))) float f32x4;

#define XS_STRIDE 72                          // [384][72] bf16 rows
#define PS_STRIDE 392                         // [128][392] bf16 (784B rows, XOR-swizzled)
#define SMEM_PS   (NL*XS_STRIDE*2)            // 55296
#define SMEM_RED  (SMEM_PS + 128*PS_STRIDE*2) // 155648
#define SMEM_TOTAL (SMEM_RED + 4096)          // 159744 <= 163840

// barrier WITHOUT vmcnt drain: orders LDS only; in-flight global->reg loads survive
#define BAR() do { asm volatile("s_waitcnt lgkmcnt(0)" ::: "memory"); \
                   __builtin_amdgcn_s_barrier(); } while (0)

__device__ __forceinline__ unsigned short bf16b(float f) {   // sw RNE (cold path)
  union { float f; unsigned u; } x; x.f = f;
  return (unsigned short)((x.u + 0x7fffu + ((x.u >> 16) & 1u)) >> 16);
}
__device__ __forceinline__ float b2f(unsigned short h) {
  union { unsigned u; float f; } x; x.u = ((unsigned)h) << 16;
  return x.f;
}
__device__ __forceinline__ unsigned short bfc(float f) {     // hw cvt (RNE)
  __bf16 h = (__bf16)f;
  return __builtin_bit_cast(unsigned short, h);
}

// ---------------- prelude: top-3 NN (blocks 0..255) + PE table (blocks 256..543) ----------------
__global__ __launch_bounds__(1024) void k_pre(const float* __restrict__ inp,
                                              int* __restrict__ idxw,
                                              unsigned short* __restrict__ peb) {
  const int t = threadIdx.x;
  if (blockIdx.x >= NS) {
    int gid = (blockIdx.x - NS) * 1024 + t;        // 288 blocks cover 384*768
    if (gid < NL * NH) {
      int l = gid / NH, d = gid - l * NH;
      const float c = -0.011992630687355995f;      // (float)(-log(1e4)/768)
      float dv = __expf((float)(d & ~1) * c);
      float ang = (float)l * dv;
      float v = (d & 1) ? cosf(ang) : sinf(ang);
      peb[gid] = bf16b(v);
    }
    return;
  }
  const int i = blockIdx.x;
  __shared__ float xi[772];                   // 4 segs of 193 (192 + 1 pad)
  __shared__ float dist[NS];
  __shared__ unsigned long long wkeys[16];
  for (int h = t; h < NH; h += 1024) xi[h + h / 192] = inp[(size_t)i * WH + h];
  __syncthreads();
  const int c = t >> 2, seg = t & 3;
  const float* __restrict__ row = inp + (size_t)c * WH + seg * 192;
  const float* xis = xi + seg * 193;
  float s = 0.f;
  #pragma unroll 4
  for (int h = 0; h < 192; h += 4) {
    float4 v = *(const float4*)(row + h);
    s += fabsf(xis[h]     - v.x) + fabsf(xis[h + 1] - v.y)
       + fabsf(xis[h + 2] - v.z) + fabsf(xis[h + 3] - v.w);
  }
  s += __shfl_xor(s, 1, 64);
  s += __shfl_xor(s, 2, 64);
  if (seg == 0) dist[c] = s;
  __syncthreads();
  for (int k = 0; k < 3; ++k) {
    float d = (t < NS) ? dist[t] : 3.4e38f;
    unsigned long long key = ((unsigned long long)__float_as_uint(d) << 32) | (unsigned)t;
    #pragma unroll
    for (int dd = 1; dd < 64; dd <<= 1) {
      unsigned long long o = __shfl_xor(key, dd, 64);
      key = (o < key) ? o : key;
    }
    if ((t & 63) == 0) wkeys[t >> 6] = key;
    __syncthreads();
    if (t == 0) {
      unsigned long long best = wkeys[0];
      for (int w = 1; w < 16; ++w) if (wkeys[w] < best) best = wkeys[w];
      int bj = (int)(best & 0xffffffffu);
      idxw[i * 3 + k] = bj;
      dist[bj] = 3.4e38f;
    }
    __syncthreads();
  }
}

// ---------------- fused attention: one block per s, 8 waves, fp32 input ----------------
__global__ __launch_bounds__(512)
void k_attn(const float* __restrict__ inp, const unsigned short* __restrict__ peb,
            const int* __restrict__ idxw, float* __restrict__ out) {
  extern __shared__ char smem[];
  unsigned short* Xs = (unsigned short*)smem;              // QK: [384][72]; PV: VT [64][392] (swizzled)
  unsigned short* Ps = (unsigned short*)(smem + SMEM_PS);  // [128][392] normalized P (bf16, swizzled)
  float* red1 = (float*)(smem + SMEM_RED);                 // [128][4]
  float* red2 = red1 + 512;                                // [128][4]

  const int s = blockIdx.x;
  const int tid = threadIdx.x;
  const int lane = tid & 63, wid = tid >> 6;
  const int lrow = lane & 15, lhi = lane >> 4;
  const int i0 = idxw[s * 3 + 0], i1 = idxw[s * 3 + 1], i2 = idxw[s * 3 + 2];

  const f32x4 fz = {0.f, 0.f, 0.f, 0.f};
  f32x4 acc[4][6];
  #pragma unroll
  for (int qs = 0; qs < 4; ++qs)
    #pragma unroll
    for (int kf = 0; kf < 6; ++kf) acc[qs][kf] = fz;

  const int qh = wid & 1, kq = wid >> 1;   // QK tiling: 64q x 96k per wave
  const int rl0 = tid >> 3, c8 = (tid & 7) * 8;

  // ============ QK^T over 12 h-chunks, x prefetched one chunk ahead ============
  float4 qx0[6], qx1[6];
  #pragma unroll
  for (int it = 0; it < 6; ++it) {
    const int src = (it < 2) ? i0 : (it < 4 ? i1 : i2);
    const int rl = rl0 + (it & 1) * 64;
    const float* px = inp + (size_t)src * WH + (size_t)rl * NH + c8;
    qx0[it] = *(const float4*)px; qx1[it] = *(const float4*)(px + 4);
  }
  for (int hc = 0; hc < 12; ++hc) {
    const int h0 = hc * 64;
    #pragma unroll
    for (int it = 0; it < 6; ++it) {
      const int rl = rl0 + (it & 1) * 64;
      const int r  = rl + (it >> 1) * 128;
      ushort8 pv = *(const ushort8*)&peb[r * NH + h0 + c8];
      float4 a = qx0[it], b = qx1[it];
      bf16x8 o;
      o[0] = (__bf16)(a.x + b2f(pv[0])); o[1] = (__bf16)(a.y + b2f(pv[1]));
      o[2] = (__bf16)(a.z + b2f(pv[2])); o[3] = (__bf16)(a.w + b2f(pv[3]));
      o[4] = (__bf16)(b.x + b2f(pv[4])); o[5] = (__bf16)(b.y + b2f(pv[5]));
      o[6] = (__bf16)(b.z + b2f(pv[6])); o[7] = (__bf16)(b.w + b2f(pv[7]));
      *reinterpret_cast<bf16x8*>(&Xs[r * XS_STRIDE + c8]) = o;
      if (hc < 11) {   // prefetch next chunk; stays in flight across BARs
        const int src = (it < 2) ? i0 : (it < 4 ? i1 : i2);
        const float* px = inp + (size_t)src * WH + (size_t)rl * NH + h0 + 64 + c8;
        qx0[it] = *(const float4*)px; qx1[it] = *(const float4*)(px + 4);
      }
    }
    BAR();
    __builtin_amdgcn_s_setprio(1);
    #pragma unroll
    for (int ks = 0; ks < 64; ks += 32) {
      short8 a[4];
      #pragma unroll
      for (int qs = 0; qs < 4; ++qs)
        a[qs] = *reinterpret_cast<const short8*>(&Xs[(qh * 64 + qs * 16 + lrow) * XS_STRIDE + ks + lhi * 8]);
      #pragma unroll
      for (int kf = 0; kf < 6; ++kf) {
        short8 b = *reinterpret_cast<const short8*>(&Xs[(kq * 96 + kf * 16 + lrow) * XS_STRIDE + ks + lhi * 8]);
        #pragma unroll
        for (int qs = 0; qs < 4; ++qs)
          acc[qs][kf] = __builtin_amdgcn_mfma_f32_16x16x32_bf16(a[qs], b, acc[qs][kf], 0, 0, 0);
      }
    }
    __builtin_amdgcn_s_setprio(0);
    BAR();
  }

  // ---- issue PV pass's first-chunk prefetch NOW; softmax hides its latency ----
  float4 vx0[6], vx1[6];
  #pragma unroll
  for (int it = 0; it < 6; ++it) {
    const int src = (it < 2) ? i0 : (it < 4 ? i1 : i2);
    const int ml = rl0 + (it & 1) * 64;
    const float* px = inp + (size_t)src * WH + (size_t)ml * NH + c8;
    vx0[it] = *(const float4*)px; vx1[it] = *(const float4*)(px + 4);
  }

  // ============ softmax (rows split across 4 kq-waves) ============
  const float scale = 0.03608439182435161f;  // 1/sqrt(768)
  float mx[4][4];
  #pragma unroll
  for (int qs = 0; qs < 4; ++qs)
    #pragma unroll
    for (int r = 0; r < 4; ++r) {
      float m = acc[qs][0][r];
      #pragma unroll
      for (int kf = 1; kf < 6; ++kf) m = fmaxf(m, acc[qs][kf][r]);
      #pragma unroll
      for (int d = 1; d < 16; d <<= 1) m = fmaxf(m, __shfl_xor(m, d, 64));
      mx[qs][r] = m;
    }
  if (lrow == 0) {
    #pragma unroll
    for (int qs = 0; qs < 4; ++qs)
      #pragma unroll
      for (int r = 0; r < 4; ++r)
        red1[(qh * 64 + qs * 16 + lhi * 4 + r) * 4 + kq] = mx[qs][r];
  }
  BAR();
  float sm[4][4];
  #pragma unroll
  for (int qs = 0; qs < 4; ++qs)
    #pragma unroll
    for (int r = 0; r < 4; ++r) {
      const int row = qh * 64 + qs * 16 + lhi * 4 + r;
      float4 m0 = *(const float4*)&red1[row * 4];
      mx[qs][r] = fmaxf(fmaxf(m0.x, m0.y), fmaxf(m0.z, m0.w));
      sm[qs][r] = 0.f;
    }
  #pragma unroll
  for (int qs = 0; qs < 4; ++qs)
    #pragma unroll
    for (int kf = 0; kf < 6; ++kf)
      #pragma unroll
      for (int r = 0; r < 4; ++r) {
        float p = __expf((acc[qs][kf][r] - mx[qs][r]) * scale);
        acc[qs][kf][r] = p;
        sm[qs][r] += p;
      }
  #pragma unroll
  for (int qs = 0; qs < 4; ++qs)
    #pragma unroll
    for (int r = 0; r < 4; ++r) {
      #pragma unroll
      for (int d = 1; d < 16; d <<= 1) sm[qs][r] += __shfl_xor(sm[qs][r], d, 64);
    }
  if (lrow == 0) {
    #pragma unroll
    for (int qs = 0; qs < 4; ++qs)
      #pragma unroll
      for (int r = 0; r < 4; ++r)
        red2[(qh * 64 + qs * 16 + lhi * 4 + r) * 4 + kq] = sm[qs][r];
  }
  BAR();
  #pragma unroll
  for (int qs = 0; qs < 4; ++qs)
    #pragma unroll
    for (int r = 0; r < 4; ++r) {
      const int row = qh * 64 + qs * 16 + lhi * 4 + r;
      float4 s0 = *(const float4*)&red2[row * 4];
      sm[qs][r] = 1.0f / ((s0.x + s0.y) + (s0.z + s0.w));
    }
  // write normalized P (bf16) -> Ps[q][m], XOR-swizzled: byte ^= ((q>>3)&7)<<4
  #pragma unroll
  for (int qs = 0; qs < 4; ++qs)
    #pragma unroll
    for (int kf = 0; kf < 6; ++kf)
      #pragma unroll
      for (int r = 0; r < 4; ++r) {
        const int row = qh * 64 + qs * 16 + lhi * 4 + r;
        const int col = kq * 96 + kf * 16 + lrow;
        *(unsigned short*)((char*)Ps + (((row * PS_STRIDE + col) * 2) ^ (((row >> 3) & 7) << 4))) =
            bfc(acc[qs][kf][r] * sm[qs][r]);
      }
  BAR();

  // ============ PV: O = P * V ============
  const int qb = wid & 3, hh = wid >> 2;   // 32q x 32h per wave per h-tile
  short8 pa[2][12];
  #pragma unroll
  for (int qs = 0; qs < 2; ++qs)
    #pragma unroll
    for (int m0 = 0; m0 < 12; ++m0) {
      const int row = qb * 32 + qs * 16 + lrow;
      pa[qs][m0] = *reinterpret_cast<const short8*>(
          (const char*)Ps + (((row * PS_STRIDE + m0 * 32 + lhi * 8) * 2) ^ (((row >> 3) & 7) << 4)));
    }

  // VT[c][m] = x[m][h0+c], elem-XOR ((c>>3)&7)<<3; b16 scatter; prefetch 1 tile ahead
  unsigned short* VT = Xs;                 // [64][392]
  for (int t4 = 0; t4 < 12; ++t4) {
    const int h0 = t4 * 64;
    #pragma unroll
    for (int it = 0; it < 6; ++it) {
      const int ml = rl0 + (it & 1) * 64;
      const int m  = ml + (it >> 1) * 128;
      ushort8 pv = *(const ushort8*)&peb[m * NH + h0 + c8];
      float4 a = vx0[it], b = vx1[it];
      float v[8];
      v[0] = a.x + b2f(pv[0]); v[1] = a.y + b2f(pv[1]);
      v[2] = a.z + b2f(pv[2]); v[3] = a.w + b2f(pv[3]);
      v[4] = b.x + b2f(pv[4]); v[5] = b.y + b2f(pv[5]);
      v[6] = b.z + b2f(pv[6]); v[7] = b.w + b2f(pv[7]);
      if (t4 < 11) {
        const int src = (it < 2) ? i0 : (it < 4 ? i1 : i2);
        const float* px = inp + (size_t)src * WH + (size_t)ml * NH + h0 + 64 + c8;
        vx0[it] = *(const float4*)px; vx1[it] = *(const float4*)(px + 4);
      }
      #pragma unroll
      for (int j = 0; j < 8; ++j) {
        const int vr = c8 + j;
        VT[((vr * PS_STRIDE) + m) ^ (((vr >> 3) & 7) << 3)] = bfc(v[j]);
      }
    }
    BAR();
    __builtin_amdgcn_s_setprio(1);
    f32x4 o00 = fz, o01 = fz, o10 = fz, o11 = fz;
    const int vr0 = hh * 32 + lrow, vr1 = vr0 + 16;
    const int sw0 = ((vr0 >> 3) & 7) << 4, sw1 = ((vr1 >> 3) & 7) << 4;
    #pragma unroll
    for (int mm = 0; mm < 12; ++mm) {
      const int moff = (mm * 32 + lhi * 8) * 2;
      short8 b0 = *reinterpret_cast<const short8*>((const char*)VT + ((vr0 * PS_STRIDE * 2 + moff) ^ sw0));
      short8 b1 = *reinterpret_cast<const short8*>((const char*)VT + ((vr1 * PS_STRIDE * 2 + moff) ^ sw1));
      o00 = __builtin_amdgcn_mfma_f32_16x16x32_bf16(pa[0][mm], b0, o00, 0, 0, 0);
      o01 = __builtin_amdgcn_mfma_f32_16x16x32_bf16(pa[0][mm], b1, o01, 0, 0, 0);
      o10 = __builtin_amdgcn_mfma_f32_16x16x32_bf16(pa[1][mm], b0, o10, 0, 0, 0);
      o11 = __builtin_amdgcn_mfma_f32_16x16x32_bf16(pa[1][mm], b1, o11, 0, 0, 0);
    }
    __builtin_amdgcn_s_setprio(0);
    float* ob = out + (size_t)s * (OUTROWS * NH) + h0 + hh * 32 + lrow;
    #pragma unroll
    for (int qs = 0; qs < 2; ++qs)
      #pragma unroll
      for (int hf = 0; hf < 2; ++hf) {
        f32x4 o = (qs == 0) ? (hf == 0 ? o00 : o01) : (hf == 0 ? o10 : o11);
        #pragma unroll
        for (int r = 0; r < 4; ++r) {
          const int q = qb * 32 + qs * 16 + lhi * 4 + r;
          if (q < OUTROWS) ob[(size_t)q * NH + hf * 16] = o[r];
        }
      }
    BAR();
  }
}

// ---------------- launch ----------------
extern "C" void kernel_launch(void* const* d_in, const int* in_sizes, int n_in,
                              void* d_out, int out_size, void* d_ws, size_t ws_size,
                              hipStream_t stream) {
  (void)in_sizes; (void)n_in; (void)out_size; (void)ws_size;
  const float* inp = (const float*)d_in[0];
  float* out = (float*)d_out;
  char* ws = (char*)d_ws;

  unsigned short* peb = (unsigned short*)ws;                     // 589824 B
  int* idxw           = (int*)(ws + 589824);                     // 3072 B

  hipLaunchKernelGGL(k_pre, dim3(256 + 288), dim3(1024), 0, stream, inp, idxw, peb);

  hipFuncSetAttribute((const void*)k_attn,
                      hipFuncAttributeMaxDynamicSharedMemorySize, SMEM_TOTAL);
  hipLaunchKernelGGL(k_attn, dim3(256), dim3(512), SMEM_TOTAL, stream,
                     inp, peb, idxw, out);
}

// Round 7
// 136.060 us; speedup vs baseline: 1.7757x; 1.7757x over previous
//
#include <hip/hip_runtime.h>

#define NS 256
#define NW 128
#define NH 768
#define NL 384          // TOPK*W keys
#define WH (NW*NH)      // 98304
#define OUTROWS 127

typedef __attribute__((ext_vector_type(8))) short short8;
typedef __attribute__((ext_vector_type(8))) unsigned short ushort8;
typedef __attribute__((ext_vector_type(8))) __bf16 bf16x8;
typedef __attribute__((ext_vector_type(4))) float f32x4;

#define XS_STRIDE 72                          // [384][72] bf16 rows
#define PS_STRIDE 392                         // [128][392] bf16 (784B rows, XOR-swizzled)
#define SMEM_PS   (NL*XS_STRIDE*2)            // 55296
#define SMEM_RED  (SMEM_PS + 128*PS_STRIDE*2) // 155648
#define SMEM_TOTAL (SMEM_RED + 4096)          // 159744 <= 163840

__device__ __forceinline__ unsigned short bf16b(float f) {   // sw RNE (cold path)
  union { float f; unsigned u; } x; x.f = f;
  return (unsigned short)((x.u + 0x7fffu + ((x.u >> 16) & 1u)) >> 16);
}
__device__ __forceinline__ float b2f(unsigned short h) {
  union { unsigned u; float f; } x; x.u = ((unsigned)h) << 16;
  return x.f;
}
__device__ __forceinline__ unsigned short bfc(float f) {     // hw cvt (RNE)
  __bf16 h = (__bf16)f;
  return __builtin_bit_cast(unsigned short, h);
}

// ---------------- prelude: top-3 NN (blocks 0..255) + PE table (blocks 256..543) ----------------
__global__ __launch_bounds__(1024) void k_pre(const float* __restrict__ inp,
                                              int* __restrict__ idxw,
                                              unsigned short* __restrict__ peb) {
  const int t = threadIdx.x;
  if (blockIdx.x >= NS) {
    int gid = (blockIdx.x - NS) * 1024 + t;        // 288 blocks cover 384*768
    if (gid < NL * NH) {
      int l = gid / NH, d = gid - l * NH;
      const float c = -0.011992630687355995f;      // (float)(-log(1e4)/768)
      float dv = __expf((float)(d & ~1) * c);
      float ang = (float)l * dv;
      float v = (d & 1) ? cosf(ang) : sinf(ang);
      peb[gid] = bf16b(v);
    }
    return;
  }
  const int i = blockIdx.x;
  __shared__ float xi[772];                   // 4 segs of 193 (192 + 1 pad)
  __shared__ float dist[NS];
  __shared__ unsigned long long wkeys[16];
  for (int h = t; h < NH; h += 1024) xi[h + h / 192] = inp[(size_t)i * WH + h];
  __syncthreads();
  const int c = t >> 2, seg = t & 3;
  const float* __restrict__ row = inp + (size_t)c * WH + seg * 192;
  const float* xis = xi + seg * 193;
  float s = 0.f;
  #pragma unroll 4
  for (int h = 0; h < 192; h += 4) {
    float4 v = *(const float4*)(row + h);
    s += fabsf(xis[h]     - v.x) + fabsf(xis[h + 1] - v.y)
       + fabsf(xis[h + 2] - v.z) + fabsf(xis[h + 3] - v.w);
  }
  s += __shfl_xor(s, 1, 64);
  s += __shfl_xor(s, 2, 64);
  if (seg == 0) dist[c] = s;
  __syncthreads();
  for (int k = 0; k < 3; ++k) {
    float d = (t < NS) ? dist[t] : 3.4e38f;
    unsigned long long key = ((unsigned long long)__float_as_uint(d) << 32) | (unsigned)t;
    #pragma unroll
    for (int dd = 1; dd < 64; dd <<= 1) {
      unsigned long long o = __shfl_xor(key, dd, 64);
      key = (o < key) ? o : key;
    }
    if ((t & 63) == 0) wkeys[t >> 6] = key;
    __syncthreads();
    if (t == 0) {
      unsigned long long best = wkeys[0];
      for (int w = 1; w < 16; ++w) if (wkeys[w] < best) best = wkeys[w];
      int bj = (int)(best & 0xffffffffu);
      idxw[i * 3 + k] = bj;
      dist[bj] = 3.4e38f;
    }
    __syncthreads();
  }
}

// ---------------- fused attention: one block per s, 8 waves, fp32 input direct ----------------
// NOTE: 512 threads / VGPR working set must stay <= 128 (empirical hipcc cap; r3/r4/r6
// all spilled past it). No register prefetch arrays.
__global__ __launch_bounds__(512)
void k_attn(const float* __restrict__ inp, const unsigned short* __restrict__ peb,
            const int* __restrict__ idxw, float* __restrict__ out) {
  extern __shared__ char smem[];
  unsigned short* Xs = (unsigned short*)smem;              // QK: [384][72]; PV: VT [64][392] (swizzled)
  unsigned short* Ps = (unsigned short*)(smem + SMEM_PS);  // [128][392] normalized P (bf16, swizzled)
  float* red1 = (float*)(smem + SMEM_RED);                 // [128][4]
  float* red2 = red1 + 512;                                // [128][4]

  const int s = blockIdx.x;
  const int tid = threadIdx.x;
  const int lane = tid & 63, wid = tid >> 6;
  const int lrow = lane & 15, lhi = lane >> 4;
  const int i0 = idxw[s * 3 + 0], i1 = idxw[s * 3 + 1], i2 = idxw[s * 3 + 2];

  const f32x4 fz = {0.f, 0.f, 0.f, 0.f};
  f32x4 acc[4][6];
  #pragma unroll
  for (int qs = 0; qs < 4; ++qs)
    #pragma unroll
    for (int kf = 0; kf < 6; ++kf) acc[qs][kf] = fz;

  const int qh = wid & 1, kq = wid >> 1;   // QK tiling: 64q x 96k per wave
  const int rl0 = tid >> 3, c8 = (tid & 7) * 8;

  // ============ QK^T: accumulate over 12 h-chunks of 64 ============
  for (int hc = 0; hc < 12; ++hc) {
    const int h0 = hc * 64;
    #pragma unroll
    for (int it = 0; it < 6; ++it) {
      const int src = (it < 2) ? i0 : (it < 4 ? i1 : i2);   // slab uniform per it
      const int rl = rl0 + (it & 1) * 64;                   // row within slab
      const int r  = rl + (it >> 1) * 128;                  // 0..383
      const float* px = inp + (size_t)src * WH + (size_t)rl * NH + h0 + c8;
      float4 a = *(const float4*)px;
      float4 b = *(const float4*)(px + 4);
      ushort8 pv = *(const ushort8*)&peb[r * NH + h0 + c8];
      bf16x8 o;
      o[0] = (__bf16)(a.x + b2f(pv[0])); o[1] = (__bf16)(a.y + b2f(pv[1]));
      o[2] = (__bf16)(a.z + b2f(pv[2])); o[3] = (__bf16)(a.w + b2f(pv[3]));
      o[4] = (__bf16)(b.x + b2f(pv[4])); o[5] = (__bf16)(b.y + b2f(pv[5]));
      o[6] = (__bf16)(b.z + b2f(pv[6])); o[7] = (__bf16)(b.w + b2f(pv[7]));
      *reinterpret_cast<bf16x8*>(&Xs[r * XS_STRIDE + c8]) = o;
    }
    __syncthreads();
    __builtin_amdgcn_s_setprio(1);
    #pragma unroll
    for (int ks = 0; ks < 64; ks += 32) {
      short8 a[4];
      #pragma unroll
      for (int qs = 0; qs < 4; ++qs)
        a[qs] = *reinterpret_cast<const short8*>(&Xs[(qh * 64 + qs * 16 + lrow) * XS_STRIDE + ks + lhi * 8]);
      #pragma unroll
      for (int kf = 0; kf < 6; ++kf) {
        short8 b = *reinterpret_cast<const short8*>(&Xs[(kq * 96 + kf * 16 + lrow) * XS_STRIDE + ks + lhi * 8]);
        #pragma unroll
        for (int qs = 0; qs < 4; ++qs)
          acc[qs][kf] = __builtin_amdgcn_mfma_f32_16x16x32_bf16(a[qs], b, acc[qs][kf], 0, 0, 0);
      }
    }
    __builtin_amdgcn_s_setprio(0);
    __syncthreads();
  }

  // ============ softmax (rows split across 4 kq-waves) ============
  const float scale = 0.03608439182435161f;  // 1/sqrt(768)
  float mx[4][4];
  #pragma unroll
  for (int qs = 0; qs < 4; ++qs)
    #pragma unroll
    for (int r = 0; r < 4; ++r) {
      float m = acc[qs][0][r];
      #pragma unroll
      for (int kf = 1; kf < 6; ++kf) m = fmaxf(m, acc[qs][kf][r]);
      #pragma unroll
      for (int d = 1; d < 16; d <<= 1) m = fmaxf(m, __shfl_xor(m, d, 64));
      mx[qs][r] = m;
    }
  if (lrow == 0) {
    #pragma unroll
    for (int qs = 0; qs < 4; ++qs)
      #pragma unroll
      for (int r = 0; r < 4; ++r)
        red1[(qh * 64 + qs * 16 + lhi * 4 + r) * 4 + kq] = mx[qs][r];
  }
  __syncthreads();
  float sm[4][4];
  #pragma unroll
  for (int qs = 0; qs < 4; ++qs)
    #pragma unroll
    for (int r = 0; r < 4; ++r) {
      const int row = qh * 64 + qs * 16 + lhi * 4 + r;
      float4 m0 = *(const float4*)&red1[row * 4];
      mx[qs][r] = fmaxf(fmaxf(m0.x, m0.y), fmaxf(m0.z, m0.w));
      sm[qs][r] = 0.f;
    }
  #pragma unroll
  for (int qs = 0; qs < 4; ++qs)
    #pragma unroll
    for (int kf = 0; kf < 6; ++kf)
      #pragma unroll
      for (int r = 0; r < 4; ++r) {
        float p = __expf((acc[qs][kf][r] - mx[qs][r]) * scale);
        acc[qs][kf][r] = p;
        sm[qs][r] += p;
      }
  #pragma unroll
  for (int qs = 0; qs < 4; ++qs)
    #pragma unroll
    for (int r = 0; r < 4; ++r) {
      #pragma unroll
      for (int d = 1; d < 16; d <<= 1) sm[qs][r] += __shfl_xor(sm[qs][r], d, 64);
    }
  if (lrow == 0) {
    #pragma unroll
    for (int qs = 0; qs < 4; ++qs)
      #pragma unroll
      for (int r = 0; r < 4; ++r)
        red2[(qh * 64 + qs * 16 + lhi * 4 + r) * 4 + kq] = sm[qs][r];
  }
  __syncthreads();
  #pragma unroll
  for (int qs = 0; qs < 4; ++qs)
    #pragma unroll
    for (int r = 0; r < 4; ++r) {
      const int row = qh * 64 + qs * 16 + lhi * 4 + r;
      float4 s0 = *(const float4*)&red2[row * 4];
      sm[qs][r] = 1.0f / ((s0.x + s0.y) + (s0.z + s0.w));
    }
  // write normalized P (bf16) -> Ps[q][m], XOR-swizzled: byte ^= ((q>>3)&7)<<4
  #pragma unroll
  for (int qs = 0; qs < 4; ++qs)
    #pragma unroll
    for (int kf = 0; kf < 6; ++kf)
      #pragma unroll
      for (int r = 0; r < 4; ++r) {
        const int row = qh * 64 + qs * 16 + lhi * 4 + r;
        const int col = kq * 96 + kf * 16 + lrow;
        *(unsigned short*)((char*)Ps + (((row * PS_STRIDE + col) * 2) ^ (((row >> 3) & 7) << 4))) =
            bfc(acc[qs][kf][r] * sm[qs][r]);
      }
  __syncthreads();

  // ============ PV: O = P * V ============
  const int qb = wid & 3, hh = wid >> 2;   // 32q x 32h per wave per h-tile
  short8 pa[2][12];
  #pragma unroll
  for (int qs = 0; qs < 2; ++qs)
    #pragma unroll
    for (int m0 = 0; m0 < 12; ++m0) {
      const int row = qb * 32 + qs * 16 + lrow;
      pa[qs][m0] = *reinterpret_cast<const short8*>(
          (const char*)Ps + (((row * PS_STRIDE + m0 * 32 + lhi * 8) * 2) ^ (((row >> 3) & 7) << 4)));
    }

  // VT[c][m] = x[m][h0+c], elem-XOR ((c>>3)&7)<<3; b16 scatter
  unsigned short* VT = Xs;                 // [64][392]
  for (int t4 = 0; t4 < 12; ++t4) {
    const int h0 = t4 * 64;
    #pragma unroll
    for (int it = 0; it < 6; ++it) {
      const int src = (it < 2) ? i0 : (it < 4 ? i1 : i2);
      const int ml = rl0 + (it & 1) * 64;
      const int m  = ml + (it >> 1) * 128;
      const float* px = inp + (size_t)src * WH + (size_t)ml * NH + h0 + c8;
      float4 a = *(const float4*)px;
      float4 b = *(const float4*)(px + 4);
      ushort8 pv = *(const ushort8*)&peb[m * NH + h0 + c8];
      float v[8];
      v[0] = a.x + b2f(pv[0]); v[1] = a.y + b2f(pv[1]);
      v[2] = a.z + b2f(pv[2]); v[3] = a.w + b2f(pv[3]);
      v[4] = b.x + b2f(pv[4]); v[5] = b.y + b2f(pv[5]);
      v[6] = b.z + b2f(pv[6]); v[7] = b.w + b2f(pv[7]);
      #pragma unroll
      for (int j = 0; j < 8; ++j) {
        const int vr = c8 + j;
        VT[((vr * PS_STRIDE) + m) ^ (((vr >> 3) & 7) << 3)] = bfc(v[j]);
      }
    }
    __syncthreads();
    __builtin_amdgcn_s_setprio(1);
    f32x4 o00 = fz, o01 = fz, o10 = fz, o11 = fz;
    const int vr0 = hh * 32 + lrow, vr1 = vr0 + 16;
    const int sw0 = ((vr0 >> 3) & 7) << 4, sw1 = ((vr1 >> 3) & 7) << 4;
    #pragma unroll
    for (int mm = 0; mm < 12; ++mm) {
      const int moff = (mm * 32 + lhi * 8) * 2;
      short8 b0 = *reinterpret_cast<const short8*>((const char*)VT + ((vr0 * PS_STRIDE * 2 + moff) ^ sw0));
      short8 b1 = *reinterpret_cast<const short8*>((const char*)VT + ((vr1 * PS_STRIDE * 2 + moff) ^ sw1));
      o00 = __builtin_amdgcn_mfma_f32_16x16x32_bf16(pa[0][mm], b0, o00, 0, 0, 0);
      o01 = __builtin_amdgcn_mfma_f32_16x16x32_bf16(pa[0][mm], b1, o01, 0, 0, 0);
      o10 = __builtin_amdgcn_mfma_f32_16x16x32_bf16(pa[1][mm], b0, o10, 0, 0, 0);
      o11 = __builtin_amdgcn_mfma_f32_16x16x32_bf16(pa[1][mm], b1, o11, 0, 0, 0);
    }
    __builtin_amdgcn_s_setprio(0);
    float* ob = out + (size_t)s * (OUTROWS * NH) + h0 + hh * 32 + lrow;
    #pragma unroll
    for (int qs = 0; qs < 2; ++qs)
      #pragma unroll
      for (int hf = 0; hf < 2; ++hf) {
        f32x4 o = (qs == 0) ? (hf == 0 ? o00 : o01) : (hf == 0 ? o10 : o11);
        #pragma unroll
        for (int r = 0; r < 4; ++r) {
          const int q = qb * 32 + qs * 16 + lhi * 4 + r;
          if (q < OUTROWS) ob[(size_t)q * NH + hf * 16] = o[r];
        }
      }
    __syncthreads();
  }
}

// ---------------- launch ----------------
extern "C" void kernel_launch(void* const* d_in, const int* in_sizes, int n_in,
                              void* d_out, int out_size, void* d_ws, size_t ws_size,
                              hipStream_t stream) {
  (void)in_sizes; (void)n_in; (void)out_size; (void)ws_size;
  const float* inp = (const float*)d_in[0];
  float* out = (float*)d_out;
  char* ws = (char*)d_ws;

  unsigned short* peb = (unsigned short*)ws;                     // 589824 B
  int* idxw           = (int*)(ws + 589824);                     // 3072 B

  hipLaunchKernelGGL(k_pre, dim3(256 + 288), dim3(1024), 0, stream, inp, idxw, peb);

  hipFuncSetAttribute((const void*)k_attn,
                      hipFuncAttributeMaxDynamicSharedMemorySize, SMEM_TOTAL);
  hipLaunchKernelGGL(k_attn, dim3(256), dim3(512), SMEM_TOTAL, stream,
                     inp, peb, idxw, out);
}

// Round 8
// 127.747 us; speedup vs baseline: 1.8912x; 1.0651x over previous
//
#include <hip/hip_runtime.h>

#define NS 256
#define NW 128
#define NH 768
#define NL 384          // TOPK*W keys
#define WH (NW*NH)      // 98304
#define OUTROWS 127

typedef __attribute__((ext_vector_type(8))) short short8;
typedef __attribute__((ext_vector_type(8))) unsigned short ushort8;
typedef __attribute__((ext_vector_type(8))) __bf16 bf16x8;
typedef __attribute__((ext_vector_type(4))) float f32x4;

#define XS2_STRIDE 136                        // QK: [384][136] bf16 (272B rows = 16 mod 128 -> conflict-free)
#define PS_STRIDE 392                         // [128][392] bf16 (784B rows, XOR-swizzled)
#define SMEM_PS   55296                       // Ps offset (QK's 104KB Xs2 overlaps it; Ps written after QK)
#define SMEM_RED  (SMEM_PS + 128*PS_STRIDE*2) // 155648
#define SMEM_TOTAL (SMEM_RED + 4096)          // 159744 <= 163840

__device__ __forceinline__ unsigned short bf16b(float f) {   // sw RNE (cold path)
  union { float f; unsigned u; } x; x.f = f;
  return (unsigned short)((x.u + 0x7fffu + ((x.u >> 16) & 1u)) >> 16);
}
__device__ __forceinline__ float b2f(unsigned short h) {
  union { unsigned u; float f; } x; x.u = ((unsigned)h) << 16;
  return x.f;
}
__device__ __forceinline__ unsigned short bfc(float f) {     // hw cvt (RNE)
  __bf16 h = (__bf16)f;
  return __builtin_bit_cast(unsigned short, h);
}

// ---- prelude, ONE launch: top3 (blk 0..255) + PE table (256..543) + bf16 precast (544..3615) ----
__global__ __launch_bounds__(1024) void k_pre(const float* __restrict__ inp,
                                              int* __restrict__ idxw,
                                              unsigned short* __restrict__ peb,
                                              unsigned short* __restrict__ inpb) {
  const int t = threadIdx.x;
  const int b = blockIdx.x;
  if (b >= 544) {               // bf16 precast: 3072 blocks x 8192 elems
    size_t base = ((size_t)(b - 544) * 1024 + t) * 8;
    float4 a = *(const float4*)(inp + base);
    float4 c = *(const float4*)(inp + base + 4);
    ushort8 o;
    o[0] = bfc(a.x); o[1] = bfc(a.y); o[2] = bfc(a.z); o[3] = bfc(a.w);
    o[4] = bfc(c.x); o[5] = bfc(c.y); o[6] = bfc(c.z); o[7] = bfc(c.w);
    *(ushort8*)(inpb + base) = o;
    return;
  }
  if (b >= NS) {                // PE table: 288 blocks cover 384*768
    int gid = (b - NS) * 1024 + t;
    int l = gid / NH, d = gid - l * NH;
    const float c = -0.011992630687355995f;      // (float)(-log(1e4)/768)
    float dv = __expf((float)(d & ~1) * c);
    float ang = (float)l * dv;
    float v = (d & 1) ? cosf(ang) : sinf(ang);
    peb[gid] = bf16b(v);
    return;
  }
  const int i = b;              // top-3 NN (stable, smallest-index ties)
  __shared__ float xi[772];                   // 4 segs of 193 (192 + 1 pad)
  __shared__ float dist[NS];
  __shared__ unsigned long long wkeys[16];
  for (int h = t; h < NH; h += 1024) xi[h + h / 192] = inp[(size_t)i * WH + h];
  __syncthreads();
  const int c = t >> 2, seg = t & 3;
  const float* __restrict__ row = inp + (size_t)c * WH + seg * 192;
  const float* xis = xi + seg * 193;
  float s = 0.f;
  #pragma unroll 4
  for (int h = 0; h < 192; h += 4) {
    float4 v = *(const float4*)(row + h);
    s += fabsf(xis[h]     - v.x) + fabsf(xis[h + 1] - v.y)
       + fabsf(xis[h + 2] - v.z) + fabsf(xis[h + 3] - v.w);
  }
  s += __shfl_xor(s, 1, 64);
  s += __shfl_xor(s, 2, 64);
  if (seg == 0) dist[c] = s;
  __syncthreads();
  for (int k = 0; k < 3; ++k) {
    float d = (t < NS) ? dist[t] : 3.4e38f;
    unsigned long long key = ((unsigned long long)__float_as_uint(d) << 32) | (unsigned)t;
    #pragma unroll
    for (int dd = 1; dd < 64; dd <<= 1) {
      unsigned long long o = __shfl_xor(key, dd, 64);
      key = (o < key) ? o : key;
    }
    if ((t & 63) == 0) wkeys[t >> 6] = key;
    __syncthreads();
    if (t == 0) {
      unsigned long long best = wkeys[0];
      for (int w = 1; w < 16; ++w) if (wkeys[w] < best) best = wkeys[w];
      int bj = (int)(best & 0xffffffffu);
      idxw[i * 3 + k] = bj;
      dist[bj] = 3.4e38f;
    }
    __syncthreads();
  }
}

// ---------------- fused attention: one block per s, 8 waves, bf16 precast input ----------------
// VGPR working set must stay <= 128 (empirical hipcc cap for 512-thr; r3/r4/r6 all spilled past).
__global__ __launch_bounds__(512)
void k_attn(const unsigned short* __restrict__ inpb, const unsigned short* __restrict__ peb,
            const int* __restrict__ idxw, float* __restrict__ out) {
  extern __shared__ char smem[];
  unsigned short* Xs = (unsigned short*)smem;              // QK: [384][136] (104KB, overlaps Ps); PV: VT [64][392]
  unsigned short* Ps = (unsigned short*)(smem + SMEM_PS);  // [128][392] normalized P (bf16, swizzled)
  float* red1 = (float*)(smem + SMEM_RED);                 // [128][4]
  float* red2 = red1 + 512;                                // [128][4]

  const int s = blockIdx.x;
  const int tid = threadIdx.x;
  const int lane = tid & 63, wid = tid >> 6;
  const int lrow = lane & 15, lhi = lane >> 4;
  const int i0 = idxw[s * 3 + 0], i1 = idxw[s * 3 + 1], i2 = idxw[s * 3 + 2];

  const f32x4 fz = {0.f, 0.f, 0.f, 0.f};
  f32x4 acc[4][6];
  #pragma unroll
  for (int qs = 0; qs < 4; ++qs)
    #pragma unroll
    for (int kf = 0; kf < 6; ++kf) acc[qs][kf] = fz;

  const int qh = wid & 1, kq = wid >> 1;   // QK tiling: 64q x 96k per wave

  // ============ QK^T: 6 h-chunks of 128 (Ps region dead -> 104KB staging legal) ============
  for (int hc = 0; hc < 6; ++hc) {
    const int h0 = hc * 128;
    #pragma unroll
    for (int it = 0; it < 12; ++it) {
      const int src = (it < 4) ? i0 : (it < 8 ? i1 : i2);   // slab uniform per it
      const int rls = (it & 3) * 32 + (tid >> 4);           // row within slab
      const int r   = it * 32 + (tid >> 4);                 // 0..383
      const int cc  = (tid & 15) * 8;
      ushort8 xv = *(const ushort8*)&inpb[(size_t)src * WH + (size_t)rls * NH + h0 + cc];
      ushort8 pv = *(const ushort8*)&peb[r * NH + h0 + cc];
      bf16x8 o;
      #pragma unroll
      for (int j = 0; j < 8; ++j) o[j] = (__bf16)(b2f(xv[j]) + b2f(pv[j]));
      *reinterpret_cast<bf16x8*>(&Xs[r * XS2_STRIDE + cc]) = o;
    }
    __syncthreads();
    __builtin_amdgcn_s_setprio(1);
    #pragma unroll
    for (int ks = 0; ks < 128; ks += 32) {
      short8 a[4];
      #pragma unroll
      for (int qs = 0; qs < 4; ++qs)
        a[qs] = *reinterpret_cast<const short8*>(&Xs[(qh * 64 + qs * 16 + lrow) * XS2_STRIDE + ks + lhi * 8]);
      #pragma unroll
      for (int kf = 0; kf < 6; ++kf) {
        short8 b = *reinterpret_cast<const short8*>(&Xs[(kq * 96 + kf * 16 + lrow) * XS2_STRIDE + ks + lhi * 8]);
        #pragma unroll
        for (int qs = 0; qs < 4; ++qs)
          acc[qs][kf] = __builtin_amdgcn_mfma_f32_16x16x32_bf16(a[qs], b, acc[qs][kf], 0, 0, 0);
      }
    }
    __builtin_amdgcn_s_setprio(0);
    __syncthreads();
  }

  // ============ softmax (rows split across 4 kq-waves) ============
  const float scale = 0.03608439182435161f;  // 1/sqrt(768)
  float mx[4][4];
  #pragma unroll
  for (int qs = 0; qs < 4; ++qs)
    #pragma unroll
    for (int r = 0; r < 4; ++r) {
      float m = acc[qs][0][r];
      #pragma unroll
      for (int kf = 1; kf < 6; ++kf) m = fmaxf(m, acc[qs][kf][r]);
      #pragma unroll
      for (int d = 1; d < 16; d <<= 1) m = fmaxf(m, __shfl_xor(m, d, 64));
      mx[qs][r] = m;
    }
  if (lrow == 0) {
    #pragma unroll
    for (int qs = 0; qs < 4; ++qs)
      #pragma unroll
      for (int r = 0; r < 4; ++r)
        red1[(qh * 64 + qs * 16 + lhi * 4 + r) * 4 + kq] = mx[qs][r];
  }
  __syncthreads();
  float sm[4][4];
  #pragma unroll
  for (int qs = 0; qs < 4; ++qs)
    #pragma unroll
    for (int r = 0; r < 4; ++r) {
      const int row = qh * 64 + qs * 16 + lhi * 4 + r;
      float4 m0 = *(const float4*)&red1[row * 4];
      mx[qs][r] = fmaxf(fmaxf(m0.x, m0.y), fmaxf(m0.z, m0.w));
      sm[qs][r] = 0.f;
    }
  #pragma unroll
  for (int qs = 0; qs < 4; ++qs)
    #pragma unroll
    for (int kf = 0; kf < 6; ++kf)
      #pragma unroll
      for (int r = 0; r < 4; ++r) {
        float p = __expf((acc[qs][kf][r] - mx[qs][r]) * scale);
        acc[qs][kf][r] = p;
        sm[qs][r] += p;
      }
  #pragma unroll
  for (int qs = 0; qs < 4; ++qs)
    #pragma unroll
    for (int r = 0; r < 4; ++r) {
      #pragma unroll
      for (int d = 1; d < 16; d <<= 1) sm[qs][r] += __shfl_xor(sm[qs][r], d, 64);
    }
  if (lrow == 0) {
    #pragma unroll
    for (int qs = 0; qs < 4; ++qs)
      #pragma unroll
      for (int r = 0; r < 4; ++r)
        red2[(qh * 64 + qs * 16 + lhi * 4 + r) * 4 + kq] = sm[qs][r];
  }
  __syncthreads();
  #pragma unroll
  for (int qs = 0; qs < 4; ++qs)
    #pragma unroll
    for (int r = 0; r < 4; ++r) {
      const int row = qh * 64 + qs * 16 + lhi * 4 + r;
      float4 s0 = *(const float4*)&red2[row * 4];
      sm[qs][r] = 1.0f / ((s0.x + s0.y) + (s0.z + s0.w));
    }
  // write normalized P (bf16) -> Ps[q][m], XOR-swizzled: byte ^= ((q>>3)&7)<<4
  #pragma unroll
  for (int qs = 0; qs < 4; ++qs)
    #pragma unroll
    for (int kf = 0; kf < 6; ++kf)
      #pragma unroll
      for (int r = 0; r < 4; ++r) {
        const int row = qh * 64 + qs * 16 + lhi * 4 + r;
        const int col = kq * 96 + kf * 16 + lrow;
        *(unsigned short*)((char*)Ps + (((row * PS_STRIDE + col) * 2) ^ (((row >> 3) & 7) << 4))) =
            bfc(acc[qs][kf][r] * sm[qs][r]);
      }
  __syncthreads();

  // ============ PV: O = P * V ============
  const int qb = wid & 3, hh = wid >> 2;   // 32q x 32h per wave per h-tile
  short8 pa[2][12];
  #pragma unroll
  for (int qs = 0; qs < 2; ++qs)
    #pragma unroll
    for (int m0 = 0; m0 < 12; ++m0) {
      const int row = qb * 32 + qs * 16 + lrow;
      pa[qs][m0] = *reinterpret_cast<const short8*>(
          (const char*)Ps + (((row * PS_STRIDE + m0 * 32 + lhi * 8) * 2) ^ (((row >> 3) & 7) << 4)));
    }

  // VT[c][m] = x[m][h0+c], elem-XOR ((c>>3)&7)<<3; b16 scatter (50KB region, below Ps)
  unsigned short* VT = Xs;                 // [64][392]
  const int rl0 = tid >> 3, c8 = (tid & 7) * 8;
  for (int t4 = 0; t4 < 12; ++t4) {
    const int h0 = t4 * 64;
    #pragma unroll
    for (int it = 0; it < 6; ++it) {
      const int src = (it < 2) ? i0 : (it < 4 ? i1 : i2);
      const int ml = rl0 + (it & 1) * 64;
      const int m  = ml + (it >> 1) * 128;
      ushort8 xv = *(const ushort8*)&inpb[(size_t)src * WH + (size_t)ml * NH + h0 + c8];
      ushort8 pv = *(const ushort8*)&peb[m * NH + h0 + c8];
      #pragma unroll
      for (int j = 0; j < 8; ++j) {
        const int vr = c8 + j;
        VT[((vr * PS_STRIDE) + m) ^ (((vr >> 3) & 7) << 3)] = bfc(b2f(xv[j]) + b2f(pv[j]));
      }
    }
    __syncthreads();
    __builtin_amdgcn_s_setprio(1);
    f32x4 o00 = fz, o01 = fz, o10 = fz, o11 = fz;
    const int vr0 = hh * 32 + lrow, vr1 = vr0 + 16;
    const int sw0 = ((vr0 >> 3) & 7) << 4, sw1 = ((vr1 >> 3) & 7) << 4;
    #pragma unroll
    for (int mm = 0; mm < 12; ++mm) {
      const int moff = (mm * 32 + lhi * 8) * 2;
      short8 b0 = *reinterpret_cast<const short8*>((const char*)VT + ((vr0 * PS_STRIDE * 2 + moff) ^ sw0));
      short8 b1 = *reinterpret_cast<const short8*>((const char*)VT + ((vr1 * PS_STRIDE * 2 + moff) ^ sw1));
      o00 = __builtin_amdgcn_mfma_f32_16x16x32_bf16(pa[0][mm], b0, o00, 0, 0, 0);
      o01 = __builtin_amdgcn_mfma_f32_16x16x32_bf16(pa[0][mm], b1, o01, 0, 0, 0);
      o10 = __builtin_amdgcn_mfma_f32_16x16x32_bf16(pa[1][mm], b0, o10, 0, 0, 0);
      o11 = __builtin_amdgcn_mfma_f32_16x16x32_bf16(pa[1][mm], b1, o11, 0, 0, 0);
    }
    __builtin_amdgcn_s_setprio(0);
    float* ob = out + (size_t)s * (OUTROWS * NH) + h0 + hh * 32 + lrow;
    #pragma unroll
    for (int qs = 0; qs < 2; ++qs)
      #pragma unroll
      for (int hf = 0; hf < 2; ++hf) {
        f32x4 o = (qs == 0) ? (hf == 0 ? o00 : o01) : (hf == 0 ? o10 : o11);
        #pragma unroll
        for (int r = 0; r < 4; ++r) {
          const int q = qb * 32 + qs * 16 + lhi * 4 + r;
          if (q < OUTROWS) ob[(size_t)q * NH + hf * 16] = o[r];
        }
      }
    __syncthreads();
  }
}

// ---------------- launch ----------------
extern "C" void kernel_launch(void* const* d_in, const int* in_sizes, int n_in,
                              void* d_out, int out_size, void* d_ws, size_t ws_size,
                              hipStream_t stream) {
  (void)in_sizes; (void)n_in; (void)out_size; (void)ws_size;
  const float* inp = (const float*)d_in[0];
  float* out = (float*)d_out;
  char* ws = (char*)d_ws;

  unsigned short* peb = (unsigned short*)ws;                     // 589824 B
  int* idxw           = (int*)(ws + 589824);                     // 3072 B
  unsigned short* inpb= (unsigned short*)(ws + 592896);          // 50331648 B

  hipLaunchKernelGGL(k_pre, dim3(256 + 288 + 3072), dim3(1024), 0, stream,
                     inp, idxw, peb, inpb);

  hipFuncSetAttribute((const void*)k_attn,
                      hipFuncAttributeMaxDynamicSharedMemorySize, SMEM_TOTAL);
  hipLaunchKernelGGL(k_attn, dim3(256), dim3(512), SMEM_TOTAL, stream,
                     inpb, peb, idxw, out);
}